// Round 9
// baseline (145.262 us; speedup 1.0000x reference)
//
#include <hip/hip_runtime.h>
#include <hip/hip_fp16.h>
#include <cmath>

// Problem constants
#define BATCH   16
#define SEQ     2048
#define IN_DIM  57
#define D_MODEL 64
#define HEADDIM 32
#define D_STATE 32
#define OUT_DIM 6
#define D_INNER 128
#define NHEADS  4
#define D_CONV  4
#define D_XBC   192          // D_INNER + 2*D_STATE
#define D_IN_PROJ 324        // 2*D_INNER + 2*D_STATE + NHEADS
#define BL      (BATCH*SEQ)  // 32768

// Chunked scan config
#define NCHUNK  64
#define CLEN    (SEQ / NCHUNK)   // 32
#define SUBL    16               // phase3 rows per block (half chunk)
#define XDS     200              // xdl row stride (halfs)

// MFMA inproj geometry: M=48 (3x16, rows 0..34 valid), K=64 (57 valid),
// N=336 (21x16, cols 0..323 valid).
#define NT      21               // n-tiles

typedef _Float16 f16x8 __attribute__((ext_vector_type(8)));
typedef _Float16 f16x2 __attribute__((ext_vector_type(2)));
typedef float    f32x4 __attribute__((ext_vector_type(4)));

// mega1 LDS map (bytes). Lifetime phases (R7 layout — conv reads from
// row-major xdl are bank-conflict-free; the R8 transposed-xd layout was a
// 10x bank-conflict regression and is reverted):
//  [inproj]  xsh 0..6144, zl 6144..14336, xdl 14336..28336
//  [conv]    Xt 0..8192, B16 8192..10240, Bt 10240..12288, C16 12288..14336
//            (xsh/zl dead), xdl still live, dtl 30720..
//  [ssd]     Ml 14336..22528 (xdl dead), Ypack 22528..30720, then S reuses Ml
#define OXT   0
#define OB16  8192
#define OBT   10240
#define OC16  12288
#define OXDL  14336
#define OML   14336
#define OSL   14336
#define OYP   22528
#define ODTL  30720
#define OLSL  31232
#define OWL2  31744
#define ODCL  32000
#define SMEM_SZ 32512

// Workspace layout (floats). zb/cb/yb/sbuf/wp hold fp16.
#define OFF_WP   ((size_t)0)                        // 10752 floats (fp16 packed W)
#define OFF_BF   ((size_t)10752)                    // 324 -> pad 336
#define OFF_WOC  ((size_t)11088)                    // 768
#define OFF_P    ((size_t)11856)                    // 4096
#define OFF_DC   ((size_t)15952)                    // BL*4 = 131072
#define OFF_ZB   ((size_t)147024)                   // BL*128 halfs
#define OFF_CB   (OFF_ZB + (size_t)BL*64)           // BL*32 halfs
#define OFF_YB   (OFF_CB + (size_t)BL*16)           // BL*128 halfs (packed frag order)
#define OFF_SB   (OFF_YB + (size_t)BL*64)           // 64*64*1024 halfs

// Swizzled half-address within a [rows][32]-half fp16 buffer (64 B rows,
// 16B-block XOR by row&3 -> aligned b128 reads, <=4-way bank conflicts).
__device__ __forceinline__ int swz(int row, int j) {
    return row * 64 + (((j >> 3) ^ (row & 3)) << 4) + ((j & 7) << 1);
}
__device__ __forceinline__ int swz4(int row, int kg) {   // uint4 read addr
    return row * 64 + ((kg ^ (row & 3)) << 4);
}

// ---------------------------------------------------------------------------
// Kernel 1: packed fp16 Wp = (W_lin@W_in) in MFMA B-fragment layout;
// bf = b_lin@W_in ; W_oc = W_out@W_cls ; out = b_cls.
__global__ void fuse_w_kernel(const float* __restrict__ W_lin,
                              const float* __restrict__ b_lin,
                              const float* __restrict__ W_in,
                              const float* __restrict__ W_out,
                              const float* __restrict__ W_cls,
                              __half* __restrict__ Wph, float* __restrict__ bf,
                              float* __restrict__ Woc,
                              const float* __restrict__ b_cls,
                              float* __restrict__ out) {
    int idx = blockIdx.x * 256 + threadIdx.x;
    if (idx < 64 * 336) {
        int k = idx / 336;
        int n = idx - k * 336;
        float acc = 0.f;
        if (k < IN_DIM && n < D_IN_PROJ) {
#pragma unroll 8
            for (int m = 0; m < D_MODEL; ++m)
                acc += W_lin[k * D_MODEL + m] * W_in[m * D_IN_PROJ + n];
        }
        int t = n >> 4, nl = n & 15;
        int kb = k >> 5, kr = k & 31;
        size_t pidx = (((size_t)(t * 2 + kb) * 64) + (kr >> 3) * 16 + nl) * 8 + (kr & 7);
        Wph[pidx] = __float2half(acc);
    } else if (idx < 64 * 336 + D_IN_PROJ) {
        int n = idx - 64 * 336;
        float acc = 0.f;
#pragma unroll 8
        for (int m = 0; m < D_MODEL; ++m)
            acc += b_lin[m] * W_in[m * D_IN_PROJ + n];
        bf[n] = acc;
    } else if (idx < 64 * 336 + D_IN_PROJ + D_INNER * OUT_DIM) {
        int idx2 = idx - (64 * 336 + D_IN_PROJ);
        int i = idx2 / OUT_DIM;
        int o = idx2 - i * OUT_DIM;
        float acc = 0.f;
#pragma unroll 8
        for (int j = 0; j < D_MODEL; ++j)
            acc += W_out[i * D_MODEL + j] * W_cls[j * OUT_DIM + o];
        Woc[i * OUT_DIM + o] = acc;
    } else if (idx < 64 * 336 + D_IN_PROJ + D_INNER * OUT_DIM + BATCH * OUT_DIM) {
        int idx3 = idx - (64 * 336 + D_IN_PROJ + D_INNER * OUT_DIM);
        out[idx3] = b_cls[idx3 % OUT_DIM];
    }
}

// ---------------------------------------------------------------------------
// Mega kernel: MFMA in-projection -> conv/SiLU/dt -> SSD chunked scan on
// MFMA (G = C.B^T, M = mask(G), Y = M.X, S = (w.X)^T-weighted . B).
// 32.5 KB LDS -> 5 blocks/CU.
__global__ __launch_bounds__(256) void mega1_kernel(
        const float* __restrict__ x,
        const __half* __restrict__ Wph, const float* __restrict__ bf,
        const float* __restrict__ conv_w, const float* __restrict__ conv_b,
        const float* __restrict__ dt_bias, const float* __restrict__ A_log,
        const float* __restrict__ Dp,
        __half* __restrict__ zbh,
        __half* __restrict__ sbuf, float* __restrict__ Pbuf,
        __half* __restrict__ ybuf, __half* __restrict__ Cbuf,
        float* __restrict__ Dcum) {
    __shared__ __align__(16) char smem[SMEM_SZ];
    __half* xsh        = (__half*)smem;                    // 48x64 fp16 [inproj]
    __half (*zl)[128]  = (__half (*)[128])(smem + 6144);   // 32x128 fp16 [inproj]
    __half (*xdl)[XDS] = (__half (*)[XDS])(smem + OXDL);   // 35x200 fp16

    int b = blockIdx.x >> 6;          // NCHUNK=64
    int c = blockIdx.x & (NCHUNK - 1);
    int tid = threadIdx.x;
    long rbase = (long)b * SEQ + (long)c * CLEN;

    // ---- stage x rows rbase-3 .. rbase+31 as fp16, XOR-swizzled ----
    for (int i = tid; i < 48 * 64; i += 256) {
        int r = i >> 6, k = i & 63;
        float v = 0.f;
        if (r < 35 && k < IN_DIM && (c > 0 || r >= 3))
            v = x[(rbase - 3 + r) * IN_DIM + k];
        xsh[i ^ ((r & 7) << 3)] = __float2half(v);
    }
    __syncthreads();

    // ---- MFMA in-projection: y[48][336] = x[48][64] @ Wf[64][336] + bf ----
    {
        int wid = tid >> 6, lane = tid & 63;
        int mrow = lane & 15, kg = lane >> 4;
        union { uint4 u; f16x8 f; } a[3][2];
#pragma unroll
        for (int mt = 0; mt < 3; ++mt)
#pragma unroll
            for (int kb = 0; kb < 2; ++kb) {
                int row = mt * 16 + mrow;
                int hidx = (row * 64 + kb * 32 + kg * 8) ^ ((row & 7) << 3);
                a[mt][kb].u = *(const uint4*)&xsh[hidx];
            }
        const uint4* wp4 = (const uint4*)Wph;
        for (int t = wid; t < NT; t += 4) {
            union { uint4 u; f16x8 f; } b0, b1;
            b0.u = wp4[(t * 2 + 0) * 64 + lane];
            b1.u = wp4[(t * 2 + 1) * 64 + lane];
            float bias = bf[t * 16 + mrow];
            f32x4 acc0 = {0.f, 0.f, 0.f, 0.f}, acc1 = acc0, acc2 = acc0;
            acc0 = __builtin_amdgcn_mfma_f32_16x16x32_f16(a[0][0].f, b0.f, acc0, 0, 0, 0);
            acc0 = __builtin_amdgcn_mfma_f32_16x16x32_f16(a[0][1].f, b1.f, acc0, 0, 0, 0);
            acc1 = __builtin_amdgcn_mfma_f32_16x16x32_f16(a[1][0].f, b0.f, acc1, 0, 0, 0);
            acc1 = __builtin_amdgcn_mfma_f32_16x16x32_f16(a[1][1].f, b1.f, acc1, 0, 0, 0);
            acc2 = __builtin_amdgcn_mfma_f32_16x16x32_f16(a[2][0].f, b0.f, acc2, 0, 0, 0);
            acc2 = __builtin_amdgcn_mfma_f32_16x16x32_f16(a[2][1].f, b1.f, acc2, 0, 0, 0);
            int n = t * 16 + mrow;
#pragma unroll
            for (int mt = 0; mt < 3; ++mt) {
                f32x4 av = (mt == 0) ? acc0 : (mt == 1) ? acc1 : acc2;
#pragma unroll
                for (int reg = 0; reg < 4; ++reg) {
                    int m = mt * 16 + kg * 4 + reg;   // C/D row [m89]
                    float v = av[reg] + bias;
                    if (t < 8) {
                        int zr = m - 3;
                        if (zr >= 0 && zr < 32) zl[zr][n] = __float2half(v);
                    } else {
                        int xc = n - 128;
                        if (m < 35 && xc < 196) xdl[m][xc] = __float2half(v);
                    }
                }
            }
        }
    }
    __syncthreads();

    // ---- flush z tile (contiguous 8 KB, coalesced) ----
    {
        const uint4* zsrc = (const uint4*)&zl[0][0];
        uint4* zdst = (uint4*)(zbh + (size_t)rbase * D_INNER);
        zdst[tid]       = zsrc[tid];
        zdst[tid + 256] = zsrc[tid + 256];
    }
    __syncthreads();   // xsh/zl dead -> Xt/B16/Bt/C16 may be written

    // ---- conv + SiLU -> fp16 operand buffers; dt -> dtl ----
    if (tid < D_INNER) {
        // x-channels: Xt[p][i]
        int p = tid;
        float w0 = conv_w[p*4+0], w1 = conv_w[p*4+1];
        float w2 = conv_w[p*4+2], w3 = conv_w[p*4+3];
        float cb = conv_b[p];
        float vm1 = 0.f, vm2 = 0.f, vm3 = 0.f;
        if (c > 0) {
            vm1 = __half2float(xdl[2][p]);
            vm2 = __half2float(xdl[1][p]);
            vm3 = __half2float(xdl[0][p]);
        }
#pragma unroll
        for (int i = 0; i < CLEN; ++i) {
            float v0 = __half2float(xdl[i + 3][p]);
            float a = cb + v0 * w3 + vm1 * w2 + vm2 * w1 + vm3 * w0;
            float sv = a / (1.f + expf(-a));
            *(__half*)(smem + OXT + swz(p, i)) = __float2half(sv);
            vm3 = vm2; vm2 = vm1; vm1 = v0;
        }
    } else if (tid < D_INNER + D_STATE) {
        // B-channels: B16[j][n] and Bt[n][j]
        int n = tid - D_INNER;
        int ch = D_INNER + n;
        float w0 = conv_w[ch*4+0], w1 = conv_w[ch*4+1];
        float w2 = conv_w[ch*4+2], w3 = conv_w[ch*4+3];
        float cb = conv_b[ch];
        float vm1 = 0.f, vm2 = 0.f, vm3 = 0.f;
        if (c > 0) {
            vm1 = __half2float(xdl[2][ch]);
            vm2 = __half2float(xdl[1][ch]);
            vm3 = __half2float(xdl[0][ch]);
        }
#pragma unroll
        for (int i = 0; i < CLEN; ++i) {
            float v0 = __half2float(xdl[i + 3][ch]);
            float a = cb + v0 * w3 + vm1 * w2 + vm2 * w1 + vm3 * w0;
            __half hv = __float2half(a / (1.f + expf(-a)));
            *(__half*)(smem + OB16 + swz(i, n)) = hv;
            *(__half*)(smem + OBT  + swz(n, i)) = hv;
            vm3 = vm2; vm2 = vm1; vm1 = v0;
        }
    } else if (tid < D_XBC) {
        // C-channels: C16[i][n]
        int n = tid - (D_INNER + D_STATE);
        int ch = D_INNER + D_STATE + n;
        float w0 = conv_w[ch*4+0], w1 = conv_w[ch*4+1];
        float w2 = conv_w[ch*4+2], w3 = conv_w[ch*4+3];
        float cb = conv_b[ch];
        float vm1 = 0.f, vm2 = 0.f, vm3 = 0.f;
        if (c > 0) {
            vm1 = __half2float(xdl[2][ch]);
            vm2 = __half2float(xdl[1][ch]);
            vm3 = __half2float(xdl[0][ch]);
        }
#pragma unroll
        for (int i = 0; i < CLEN; ++i) {
            float v0 = __half2float(xdl[i + 3][ch]);
            float a = cb + v0 * w3 + vm1 * w2 + vm2 * w1 + vm3 * w0;
            *(__half*)(smem + OC16 + swz(i, n)) = __float2half(a / (1.f + expf(-a)));
            vm3 = vm2; vm2 = vm1; vm1 = v0;
        }
    } else {
        // dt: dtl[h][i] = softplus(v + dt_bias)
        int idx = tid - D_XBC;       // 0..63
        int h = idx >> 4;
        int i0 = idx & 15;
        float db = dt_bias[h];
        float* dtl = (float*)(smem + ODTL);
#pragma unroll
        for (int i = i0; i < CLEN; i += 16) {
            float v = __half2float(xdl[i + 3][192 + h]) + db;
            dtl[h * 32 + i] = (v > 20.f) ? v : log1pf(expf(v));
        }
    }
    __syncthreads();   // operands ready; xdl dead

    // ---- SSD scan: one head per warp ----
    int h = tid >> 6, l = tid & 63;
    int col = l & 15, kg = l >> 4;
    int li = l & 31;
    float nA = -expf(A_log[h]);
    float Dh = Dp[h];
    float* dtl = (float*)(smem + ODTL);
    float* lsl = (float*)(smem + OLSL);
    float* dcl = (float*)(smem + ODCL);
    __half2* wl2 = (__half2*)(smem + OWL2);

    // log-decay prefix (lanes 0..31; 32..63 duplicate harmlessly)
    {
        float dtv = dtl[h * 32 + li];
        float ls = dtv * nA;
#pragma unroll
        for (int d = 1; d < 32; d <<= 1) {
            float t = __shfl_up(ls, d, 32);
            if (li >= d) ls += t;
        }
        float cd = expf(ls);
        float lsE = __shfl(ls, 31, 32);
        float w = expf(lsE - ls) * dtv;
        float wn = __shfl_down(w, 1, 32);
        if (l < 32) {
            lsl[h * 32 + li] = ls;
            dcl[li * 4 + h] = cd;
            if ((li & 1) == 0) wl2[h * 16 + (li >> 1)] = __floats2half2_rn(w, wn);
            if (li == 31) Pbuf[(b * NHEADS + h) * NCHUNK + c] = cd;
        }
    }

    // G = C . B^T   (4 MFMA)
    f32x4 g[2][2];
    {
        union { uint4 u; f16x8 f; } ac[2], bb[2];
#pragma unroll
        for (int mt = 0; mt < 2; ++mt)
            ac[mt].u = *(const uint4*)(smem + OC16 + swz4(mt * 16 + col, kg));
#pragma unroll
        for (int nt = 0; nt < 2; ++nt)
            bb[nt].u = *(const uint4*)(smem + OB16 + swz4(nt * 16 + col, kg));
#pragma unroll
        for (int mt = 0; mt < 2; ++mt)
#pragma unroll
            for (int nt = 0; nt < 2; ++nt) {
                f32x4 z = {0.f, 0.f, 0.f, 0.f};
                g[mt][nt] = __builtin_amdgcn_mfma_f32_16x16x32_f16(ac[mt].f, bb[nt].f, z, 0, 0, 0);
            }
    }

    // M[i][j] = j<i ? G*exp(ls_i-ls_j)*dt_j : j==i ? G*dt_i + Dh : 0
    {
        const float* lslh = lsl + h * 32;
        const float* dtlh = dtl + h * 32;
#pragma unroll
        for (int nt = 0; nt < 2; ++nt) {
            int j = nt * 16 + col;
            float lsj = lslh[j], dtj = dtlh[j];
#pragma unroll
            for (int mt = 0; mt < 2; ++mt)
#pragma unroll
                for (int r = 0; r < 4; ++r) {
                    int i = mt * 16 + kg * 4 + r;
                    float mv = 0.f;
                    if (j < i)       mv = g[mt][nt][r] * expf(lslh[i] - lsj) * dtj;
                    else if (j == i) mv = g[mt][nt][r] * dtj + Dh;
                    *(__half*)(smem + OML + h * 2048 + swz(i, j)) = __float2half(mv);
                }
        }
    }

    // Y = M . X   (4 MFMA) -> pack fragment-order into Ypack
    {
        union { uint4 u; f16x8 f; } am[2], bx[2];
#pragma unroll
        for (int mt = 0; mt < 2; ++mt)
            am[mt].u = *(const uint4*)(smem + OML + h * 2048 + swz4(mt * 16 + col, kg));
#pragma unroll
        for (int nt = 0; nt < 2; ++nt)
            bx[nt].u = *(const uint4*)(smem + OXT + swz4(h * 32 + nt * 16 + col, kg));
        f32x4 y[2][2];
#pragma unroll
        for (int mt = 0; mt < 2; ++mt)
#pragma unroll
            for (int nt = 0; nt < 2; ++nt) {
                f32x4 z = {0.f, 0.f, 0.f, 0.f};
                y[mt][nt] = __builtin_amdgcn_mfma_f32_16x16x32_f16(am[mt].f, bx[nt].f, z, 0, 0, 0);
            }
#pragma unroll
        for (int mt = 0; mt < 2; ++mt) {
            __half2 hp[4];
            hp[0] = __floats2half2_rn(y[mt][0][0], y[mt][0][1]);
            hp[1] = __floats2half2_rn(y[mt][0][2], y[mt][0][3]);
            hp[2] = __floats2half2_rn(y[mt][1][0], y[mt][1][1]);
            hp[3] = __floats2half2_rn(y[mt][1][2], y[mt][1][3]);
            *(uint4*)(smem + OYP + mt * 4096 + (h * 64 + l) * 16) = *(uint4*)hp;
        }
    }

    // S = (w*X)^T-form . B  (4 MFMA) -> stage linear [h][p][n]
    {
        union { uint4 u; __half2 p[4]; f16x8 f; } aw[2], bt[2];
#pragma unroll
        for (int mt = 0; mt < 2; ++mt) {
            aw[mt].u = *(const uint4*)(smem + OXT + swz4(h * 32 + mt * 16 + col, kg));
            const __half2* wp = wl2 + h * 16 + kg * 4;
#pragma unroll
            for (int t = 0; t < 4; ++t) aw[mt].p[t] = __hmul2(aw[mt].p[t], wp[t]);
        }
#pragma unroll
        for (int nt = 0; nt < 2; ++nt)
            bt[nt].u = *(const uint4*)(smem + OBT + swz4(nt * 16 + col, kg));
        f32x4 s[2][2];
#pragma unroll
        for (int mt = 0; mt < 2; ++mt)
#pragma unroll
            for (int nt = 0; nt < 2; ++nt) {
                f32x4 z = {0.f, 0.f, 0.f, 0.f};
                s[mt][nt] = __builtin_amdgcn_mfma_f32_16x16x32_f16(aw[mt].f, bt[nt].f, z, 0, 0, 0);
            }
#pragma unroll
        for (int mt = 0; mt < 2; ++mt)
#pragma unroll
            for (int nt = 0; nt < 2; ++nt)
#pragma unroll
                for (int r = 0; r < 4; ++r) {
                    int p = mt * 16 + kg * 4 + r;
                    int n = nt * 16 + col;
                    *(__half*)(smem + OSL + h * 2048 + p * 64 + n * 2) =
                        __float2half(s[mt][nt][r]);
                }
    }
    __syncthreads();

    // ---- flushes (all coalesced) ----
#pragma unroll
    for (int k2 = 0; k2 < 2; ++k2) {
        int idx = tid + k2 * 256;          // 0..511 uint4
        int hh = idx >> 7, off = idx & 127;
        *(uint4*)(sbuf + (((size_t)(b * NHEADS + hh) * NCHUNK + c) << 10) + off * 8) =
            *(uint4*)(smem + OSL + hh * 2048 + off * 16);
    }
#pragma unroll
    for (int k2 = 0; k2 < 2; ++k2) {
        int idx = tid + k2 * 256;          // 0..511 uint4
        int mt = idx >> 8, off = idx & 255;
        *(uint4*)(ybuf + (size_t)rbase * D_INNER + mt * 2048 + off * 8) =
            *(uint4*)(smem + OYP + mt * 4096 + off * 16);
    }
    if (tid < 128) {
        int i = tid >> 2, blk = tid & 3;
        *(uint4*)(Cbuf + ((size_t)rbase + i) * D_STATE + blk * 8) =
            *(uint4*)(smem + OC16 + i * 64 + ((blk ^ (i & 3)) << 4));
    }
    if (tid < 128) Dcum[(size_t)rbase * 4 + tid] = dcl[tid];
}

// ---------------------------------------------------------------------------
// Phase 2 (parallel): LDS-staged chunk-state combine. (unchanged)
__global__ __launch_bounds__(256) void scan_phase2_kernel(
        __half* __restrict__ sbuf, const float* __restrict__ Pbuf) {
    __shared__ unsigned sl[NCHUNK][128];   // 32 KB
    __shared__ float Pl[NCHUNK];
    int bh = blockIdx.x >> 2;
    int q  = blockIdx.x & 3;
    int tid = threadIdx.x;
    unsigned* s32 = (unsigned*)sbuf;
    size_t base = (size_t)bh * NCHUNK * 512 + (size_t)q * 128;
    if (tid < NCHUNK) Pl[tid] = Pbuf[bh * NCHUNK + tid];
    for (int k = tid; k < NCHUNK * 128; k += 256) {
        int c = k >> 7, j = k & 127;
        sl[c][j] = s32[base + (size_t)c * 512 + j];
    }
    __syncthreads();
    if (tid < 128) {
        float rx = 0.f, ry = 0.f;
        unsigned v = sl[0][tid];
#pragma unroll 8
        for (int c = 0; c < NCHUNK; ++c) {
            unsigned vn = (c + 1 < NCHUNK) ? sl[c + 1][tid] : 0u;
            float Pv = Pl[c];
            __half2 hv = *(__half2*)&v;
            float2 t = __half22float2(hv);
            __half2 hr = __floats2half2_rn(rx, ry);
            sl[c][tid] = *(unsigned*)&hr;
            rx = rx * Pv + t.x;
            ry = ry * Pv + t.y;
            v = vn;
        }
    }
    __syncthreads();
    for (int k = tid; k < NCHUNK * 128; k += 256) {
        int c = k >> 7, j = k & 127;
        s32[base + (size_t)c * 512 + j] = sl[c][j];
    }
}

// ---------------------------------------------------------------------------
// Phase 3 (half-chunk): y = y_u + cumdec*(C·seed) via fdot2, gate*silu(z),
// RMSNorm, head accumulation into out.
__global__ __launch_bounds__(256) void scan_phase3_kernel(
        const __half* __restrict__ ybuf, const __half* __restrict__ Cbuf,
        const float* __restrict__ Dcum, const __half* __restrict__ zbh,
        const __half* __restrict__ sbuf, const float* __restrict__ norm_w,
        const float* __restrict__ Woc, float* __restrict__ out) {
    int b  = blockIdx.x >> 7;         // 128 subchunks per batch
    int sc = blockIdx.x & 127;        // subchunk index
    int c  = sc >> 1;                 // parent chunk (seed source)
    int tid = threadIdx.x;
    __shared__ float ylds[SUBL][D_INNER];   // 8 KB
    __shared__ float dcl[SUBL * 4];         // 256 B
    __shared__ float red[4][D_INNER];       // 2 KB
    __shared__ float snw[D_INNER];          // 512 B
    size_t rbase = (size_t)b * SEQ + (size_t)sc * SUBL;
    int h = tid >> 6, lane = tid & 63;
    int p = lane >> 1, n0 = (lane & 1) * 16;
    int bh = b * NHEADS + h;
    // seed load (kept packed as 8x half2 for fdot2)
    const uint4* sp = (const uint4*)(sbuf + ((size_t)bh * NCHUNK + c) * 1024) + lane * 2;
    union { uint4 u[2]; f16x2 h2[8]; } sd;
    sd.u[0] = sp[0];
    sd.u[1] = sp[1];
    // stage packed y_u -> fp32 LDS
    {
        const __half2* ysrc = (const __half2*)(
            ybuf + ((size_t)b * SEQ + (size_t)c * CLEN) * D_INNER + (size_t)(sc & 1) * 2048);
#pragma unroll
        for (int k = 0; k < 4; ++k) {
            int idx = tid + k * 256;          // 0..1023 half2
            float2 f = __half22float2(ysrc[idx]);
            int pos = idx * 2;                // [h(4)][lane(64)][nt(2)][r(4)]
            int hh = pos >> 9;
            int rem = pos & 511;
            int fl = rem >> 3;
            int rr = rem & 7;
            int nt = rr >> 2, r0 = rr & 3;    // r0 even
            int row = ((fl >> 4) << 2) + r0;
            int colc = hh * 32 + nt * 16 + (fl & 15);
            ylds[row][colc]     = f.x;
            ylds[row + 1][colc] = f.y;
        }
    }
    if (tid < SUBL * 4) dcl[tid] = Dcum[rbase * 4 + tid];
    __syncthreads();
#pragma unroll 4
    for (int i = 0; i < SUBL; ++i) {
        const uint4* cp = (const uint4*)(Cbuf + (rbase + i) * D_STATE + n0);
        union { uint4 u[2]; f16x2 h2[8]; } cv;
        cv.u[0] = cp[0];
        cv.u[1] = cp[1];
        float part = 0.f;
#pragma unroll
        for (int k = 0; k < 8; ++k)
            part = __builtin_amdgcn_fdot2(cv.h2[k], sd.h2[k], part, false);
        part += __shfl_xor(part, 1);
        if ((lane & 1) == 0)
            ylds[i][h * HEADDIM + p] += dcl[i * 4 + h] * part;
    }
    __syncthreads();
    float acc0 = 0.f, acc1 = 0.f;
    for (int r = h; r < SUBL; r += 4) {
        size_t bl = rbase + r;
        float2 yv = *(const float2*)(&ylds[r][lane * 2]);
        float2 zv = __half22float2(*((const __half2*)(zbh + bl * D_INNER) + lane));
        float g0 = yv.x * (zv.x / (1.f + expf(-zv.x)));
        float g1 = yv.y * (zv.y / (1.f + expf(-zv.y)));
        float sq = g0 * g0 + g1 * g1;
#pragma unroll
        for (int m = 1; m < 64; m <<= 1) sq += __shfl_xor(sq, m);
        float rms = 1.0f / sqrtf(sq * (1.f / 128.f) + 1e-5f);
        acc0 += g0 * rms;
        acc1 += g1 * rms;
    }
    red[h][lane * 2]     = acc0;
    red[h][lane * 2 + 1] = acc1;
    __syncthreads();
    if (tid < D_INNER)
        snw[tid] = (red[0][tid] + red[1][tid] + red[2][tid] + red[3][tid])
                   * norm_w[tid];
    __syncthreads();
    if (tid < OUT_DIM) {
        float acc = 0.f;
#pragma unroll 8
        for (int i = 0; i < D_INNER; ++i)
            acc += snw[i] * Woc[i * OUT_DIM + tid];
        atomicAdd(&out[b * OUT_DIM + tid], acc * (1.f / (float)SEQ));
    }
}

// ---------------------------------------------------------------------------
extern "C" void kernel_launch(void* const* d_in, const int* in_sizes, int n_in,
                              void* d_out, int out_size, void* d_ws, size_t ws_size,
                              hipStream_t stream) {
    const float* x       = (const float*)d_in[0];
    const float* W_lin   = (const float*)d_in[1];
    const float* b_lin   = (const float*)d_in[2];
    const float* W_in    = (const float*)d_in[3];
    const float* conv_w  = (const float*)d_in[4];
    const float* conv_b  = (const float*)d_in[5];
    const float* dt_bias = (const float*)d_in[6];
    const float* A_log   = (const float*)d_in[7];
    const float* Dp      = (const float*)d_in[8];
    const float* norm_w  = (const float*)d_in[9];
    const float* W_out   = (const float*)d_in[10];
    const float* W_cls   = (const float*)d_in[11];
    const float* b_cls   = (const float*)d_in[12];
    float* out = (float*)d_out;

    float* ws = (float*)d_ws;
    __half* Wph  = (__half*)(ws + OFF_WP);
    float* bf    = ws + OFF_BF;
    float* Woc   = ws + OFF_WOC;
    float* Pbuf  = ws + OFF_P;
    float* Dcum  = ws + OFF_DC;
    __half* zbh  = (__half*)(ws + OFF_ZB);
    __half* Cbh  = (__half*)(ws + OFF_CB);
    __half* ybh  = (__half*)(ws + OFF_YB);
    __half* sbuf = (__half*)(ws + OFF_SB);

    // 1) fused weight precompute
    int nfw = 64 * 336 + D_IN_PROJ + D_INNER * OUT_DIM + BATCH * OUT_DIM;
    fuse_w_kernel<<<(nfw + 255) / 256, 256, 0, stream>>>(
        W_lin, b_lin, W_in, W_out, W_cls, Wph, bf, Woc, b_cls, out);

    // 2) mega kernel: MFMA inproj + conv + SSD MFMA scan per chunk
    mega1_kernel<<<BATCH * NCHUNK, 256, 0, stream>>>(
        x, Wph, bf, conv_w, conv_b, dt_bias, A_log, Dp,
        zbh, sbuf, Pbuf, ybh, Cbh, Dcum);

    // 3) parallel LDS-staged chunk-state combine
    scan_phase2_kernel<<<256, 256, 0, stream>>>(sbuf, Pbuf);

    // 4) half-chunk correction + gating + RMSNorm + head accumulation
    scan_phase3_kernel<<<BATCH * 128, 256, 0, stream>>>(
        ybh, Cbh, Dcum, zbh, sbuf, norm_w, Woc, out);
}